// Round 4
// baseline (930.968 us; speedup 1.0000x reference)
//
#include <hip/hip_runtime.h>

// DispCorrLayer: out[b,d,h,w] = (1/C) * sum_c in1[b,c,h,w] * in2[b,c,h,w-(D-d)]
// (zero when w + d < D). B=4 C=32 H=256 W=512 D=128, fp32.
//
// R4: block = (b, h, w-half of 256). in1 fetched exactly once; in2 ~1.2x.
// Channels staged in 4 chunks of 8 as bf16, double-buffered (20 KB LDS ->
// 2 blocks/CU, 4 waves/SIMD). T14 split staging: global loads issued before
// the chunk's compute, LDS writes after. Per-wave tile 16d x 256w; per lane
// 8d x 8w (acc[8][8]); 3 ds_read_b128 per channel per wave, all dense 16B.

#define BB 4
#define CC 32
#define HH 256
#define WW 512
#define DD 128

#define WHALF 256
#define S2W 384              // staged w' window: [wbase-128, wbase+256)
#define NT 512               // 8 waves
#define CCH 8                // channels per chunk
#define NCH (CC / CCH)       // 4 chunks

__device__ __forceinline__ float bflo(unsigned int u) {
    union { unsigned int i; float f; } v; v.i = u << 16; return v.f;
}
__device__ __forceinline__ float bfhi(unsigned int u) {
    union { unsigned int i; float f; } v; v.i = u & 0xffff0000u; return v.f;
}
__device__ __forceinline__ unsigned int pack2(float a, float b) {
    // RNE bf16 round: a -> low half, b -> high half
    union { float f; unsigned int i; } x, y; x.f = a; y.f = b;
    unsigned int xi = x.i + 0x7fffu + ((x.i >> 16) & 1u);
    unsigned int yi = y.i + 0x7fffu + ((y.i >> 16) & 1u);
    return (xi >> 16) | (yi & 0xffff0000u);
}

__global__ __launch_bounds__(NT, 4)
void disp_corr_kernel(const float* __restrict__ in1,
                      const float* __restrict__ in2,
                      float* __restrict__ out) {
    __shared__ unsigned int s1[2][CCH][WHALF / 2];   // bf16x2, 4 KB per buf
    __shared__ unsigned int s2[2][CCH][S2W / 2];     // bf16x2, 6 KB per buf

    const int tid = threadIdx.x;

    // XCD-pairing swizzle: blockIdx = 8t + x; the two w-halves of one (b,h)
    // land on the same XCD (shared in2 halo hits that XCD's L2). Bijective.
    const int xcd = blockIdx.x & 7, slot = blockIdx.x >> 3;
    const int work = ((xcd << 7) + (slot >> 1)) * 2 + (slot & 1);
    const int wh = work & 1;
    const int h  = (work >> 1) & (HH - 1);
    const int b  = work >> 9;
    const int wbase = wh * WHALF;

    const size_t cstr = (size_t)HH * WW;
    const float* p1 = in1 + (size_t)b * CC * cstr + (size_t)h * WW + wbase;
    const float* p2 = in2 + (size_t)b * CC * cstr + (size_t)h * WW;

    // staging assignments (constant per thread)
    const int i1c = tid >> 6, i1q = tid & 63;        // in1: 8 rows x 64 quads
    const int c2a = tid / 96, q2a = tid - c2a * 96;  // in2: 8 rows x 96 quads
    const int ib  = tid + NT;
    const int c2b = ib / 96,  q2b = ib - c2b * 96;
    const bool has2b = (tid < CCH * (S2W / 4) - NT); // tid < 256

    float4 r1  = make_float4(0.f, 0.f, 0.f, 0.f);
    float4 r2a = r1, r2b = r1;

    auto issue = [&](int ck) {        // global -> regs (issued early)
        const int cb = ck * CCH;
        r1 = *(const float4*)(p1 + (size_t)(cb + i1c) * cstr + i1q * 4);
        const int wq = wbase + q2a * 4 - DD;
        r2a = (wq >= 0) ? *(const float4*)(p2 + (size_t)(cb + c2a) * cstr + wq)
                        : make_float4(0.f, 0.f, 0.f, 0.f);
        if (has2b) {
            const int wq2 = wbase + q2b * 4 - DD;
            r2b = (wq2 >= 0) ? *(const float4*)(p2 + (size_t)(cb + c2b) * cstr + wq2)
                             : make_float4(0.f, 0.f, 0.f, 0.f);
        }
    };
    auto commit = [&](int n) {        // regs -> LDS (after compute)
        unsigned int* d1 = &s1[n][i1c][i1q * 2];
        d1[0] = pack2(r1.x, r1.y); d1[1] = pack2(r1.z, r1.w);
        unsigned int* d2 = &s2[n][c2a][q2a * 2];
        d2[0] = pack2(r2a.x, r2a.y); d2[1] = pack2(r2a.z, r2a.w);
        if (has2b) {
            unsigned int* d3 = &s2[n][c2b][q2b * 2];
            d3[0] = pack2(r2b.x, r2b.y); d3[1] = pack2(r2b.z, r2b.w);
        }
    };

    // compute decode: wave wv, lane half picks d; 32 w-slots of 8 per lane
    const int lane = tid & 63;
    const int wv   = tid >> 6;
    const int lw   = lane & 31;
    const int dloc = (wv << 4) + ((lane >> 5) << 3);   // 0..120, step 8
    const int t0   = (lw << 3) + dloc;                 // s2 float index base

    float acc[8][8] = {};

    issue(0);
    commit(0);
    __syncthreads();

    for (int k = 0; k < NCH; ++k) {
        const int cur = k & 1;
        if (k + 1 < NCH) issue(k + 1);
        #pragma unroll
        for (int c = 0; c < CCH; ++c) {
            const uint4 av = *(const uint4*)&s1[cur][c][lw * 4];
            const uint4 wa = *(const uint4*)&s2[cur][c][(t0 >> 1)];
            const uint4 wb = *(const uint4*)&s2[cur][c][(t0 >> 1) + 4];
            float a[8] = { bflo(av.x), bfhi(av.x), bflo(av.y), bfhi(av.y),
                           bflo(av.z), bfhi(av.z), bflo(av.w), bfhi(av.w) };
            float wn[16] = { bflo(wa.x), bfhi(wa.x), bflo(wa.y), bfhi(wa.y),
                             bflo(wa.z), bfhi(wa.z), bflo(wa.w), bfhi(wa.w),
                             bflo(wb.x), bfhi(wb.x), bflo(wb.y), bfhi(wb.y),
                             bflo(wb.z), bfhi(wb.z), bflo(wb.w), bfhi(wb.w) };
            #pragma unroll
            for (int di = 0; di < 8; ++di)
                #pragma unroll
                for (int wi = 0; wi < 8; ++wi)
                    acc[di][wi] += a[wi] * wn[di + wi];
        }
        if (k + 1 < NCH) commit((k + 1) & 1);
        __syncthreads();
    }

    // epilogue: per di, lanes 0-31 cover one d-row's 256 w (2x float4 each)
    const float sc = 1.0f / (float)CC;
    #pragma unroll
    for (int di = 0; di < 8; ++di) {
        const int d = dloc + di;
        float* po = out + (((size_t)b * DD + d) * HH + h) * WW + wbase + lw * 8;
        float4 o0 = make_float4(acc[di][0] * sc, acc[di][1] * sc,
                                acc[di][2] * sc, acc[di][3] * sc);
        float4 o1 = make_float4(acc[di][4] * sc, acc[di][5] * sc,
                                acc[di][6] * sc, acc[di][7] * sc);
        ((float4*)po)[0] = o0;
        ((float4*)po)[1] = o1;
    }
}

extern "C" void kernel_launch(void* const* d_in, const int* in_sizes, int n_in,
                              void* d_out, int out_size, void* d_ws, size_t ws_size,
                              hipStream_t stream) {
    const float* in1 = (const float*)d_in[0];
    const float* in2 = (const float*)d_in[1];
    float* out = (float*)d_out;
    const int nblocks = BB * HH * 2;          // 2048
    disp_corr_kernel<<<nblocks, NT, 0, stream>>>(in1, in2, out);
}

// Round 5
// 225.658 us; speedup vs baseline: 4.1256x; 4.1256x over previous
//
#include <hip/hip_runtime.h>

// DispCorrLayer: out[b,d,h,w] = (1/C) * sum_c in1[b,c,h,w] * in2[b,c,h,w-(D-d)]
// (zero when w + d < D). B=4 C=32 H=256 W=512 D=128, fp32.
//
// R5 = R4 with ONE change: __launch_bounds__(512, 1) instead of (512, 4).
// R4's (512,4) was interpreted as min-blocks/CU -> 32 waves/CU -> 64-VGPR cap
// -> acc[8][8] spilled to scratch (FETCH 1.3GB, WRITE 2.8GB, 931us).
// (512,1) -> 256-VGPR cap; pipeline needs ~120 VGPRs, no spill.
//
// Structure: block = (b, h, w-half of 256). in1 fetched exactly once; in2
// ~1.2x. Channels staged in 4 chunks of 8 as bf16, double-buffered (20 KB
// LDS). T14 split staging: global loads issued before the chunk's compute,
// LDS writes after. Per-wave tile 16d x 256w; per lane 8d x 8w (acc[8][8]);
// 3 ds_read_b128 per channel per wave, all dense 16B-per-lane patterns.

#define BB 4
#define CC 32
#define HH 256
#define WW 512
#define DD 128

#define WHALF 256
#define S2W 384              // staged w' window: [wbase-128, wbase+256)
#define NT 512               // 8 waves
#define CCH 8                // channels per chunk
#define NCH (CC / CCH)       // 4 chunks

__device__ __forceinline__ float bflo(unsigned int u) {
    union { unsigned int i; float f; } v; v.i = u << 16; return v.f;
}
__device__ __forceinline__ float bfhi(unsigned int u) {
    union { unsigned int i; float f; } v; v.i = u & 0xffff0000u; return v.f;
}
__device__ __forceinline__ unsigned int pack2(float a, float b) {
    // RNE bf16 round: a -> low half, b -> high half
    union { float f; unsigned int i; } x, y; x.f = a; y.f = b;
    unsigned int xi = x.i + 0x7fffu + ((x.i >> 16) & 1u);
    unsigned int yi = y.i + 0x7fffu + ((y.i >> 16) & 1u);
    return (xi >> 16) | (yi & 0xffff0000u);
}

__global__ __launch_bounds__(NT, 1)
void disp_corr_kernel(const float* __restrict__ in1,
                      const float* __restrict__ in2,
                      float* __restrict__ out) {
    __shared__ unsigned int s1[2][CCH][WHALF / 2];   // bf16x2, 4 KB per buf
    __shared__ unsigned int s2[2][CCH][S2W / 2];     // bf16x2, 6 KB per buf

    const int tid = threadIdx.x;

    // XCD-pairing swizzle: the two w-halves of one (b,h) land on the same XCD
    // (shared in2 halo hits that XCD's L2). Bijective for 2048 blocks.
    const int xcd = blockIdx.x & 7, slot = blockIdx.x >> 3;
    const int work = ((xcd << 7) + (slot >> 1)) * 2 + (slot & 1);
    const int wh = work & 1;
    const int h  = (work >> 1) & (HH - 1);
    const int b  = work >> 9;
    const int wbase = wh * WHALF;

    const size_t cstr = (size_t)HH * WW;
    const float* p1 = in1 + (size_t)b * CC * cstr + (size_t)h * WW + wbase;
    const float* p2 = in2 + (size_t)b * CC * cstr + (size_t)h * WW;

    // staging assignments (constant per thread)
    const int i1c = tid >> 6, i1q = tid & 63;        // in1: 8 rows x 64 quads
    const int c2a = tid / 96, q2a = tid - c2a * 96;  // in2: 8 rows x 96 quads
    const int ib  = tid + NT;
    const int c2b = ib / 96,  q2b = ib - c2b * 96;
    const bool has2b = (tid < CCH * (S2W / 4) - NT); // tid < 256

    float4 r1  = make_float4(0.f, 0.f, 0.f, 0.f);
    float4 r2a = r1, r2b = r1;

    auto issue = [&](int ck) {        // global -> regs (issued early)
        const int cb = ck * CCH;
        r1 = *(const float4*)(p1 + (size_t)(cb + i1c) * cstr + i1q * 4);
        const int wq = wbase + q2a * 4 - DD;
        r2a = (wq >= 0) ? *(const float4*)(p2 + (size_t)(cb + c2a) * cstr + wq)
                        : make_float4(0.f, 0.f, 0.f, 0.f);
        if (has2b) {
            const int wq2 = wbase + q2b * 4 - DD;
            r2b = (wq2 >= 0) ? *(const float4*)(p2 + (size_t)(cb + c2b) * cstr + wq2)
                             : make_float4(0.f, 0.f, 0.f, 0.f);
        }
    };
    auto commit = [&](int n) {        // regs -> LDS (after compute)
        unsigned int* d1 = &s1[n][i1c][i1q * 2];
        d1[0] = pack2(r1.x, r1.y); d1[1] = pack2(r1.z, r1.w);
        unsigned int* d2 = &s2[n][c2a][q2a * 2];
        d2[0] = pack2(r2a.x, r2a.y); d2[1] = pack2(r2a.z, r2a.w);
        if (has2b) {
            unsigned int* d3 = &s2[n][c2b][q2b * 2];
            d3[0] = pack2(r2b.x, r2b.y); d3[1] = pack2(r2b.z, r2b.w);
        }
    };

    // compute decode: wave wv + lane-half pick d; 32 w-slots of 8 per lane
    const int lane = tid & 63;
    const int wv   = tid >> 6;
    const int lw   = lane & 31;
    const int dloc = (wv << 4) + ((lane >> 5) << 3);   // 0..120, step 8
    const int t0   = (lw << 3) + dloc;                 // s2 float index base

    float acc[8][8] = {};

    issue(0);
    commit(0);
    __syncthreads();

    for (int k = 0; k < NCH; ++k) {
        const int cur = k & 1;
        if (k + 1 < NCH) issue(k + 1);
        #pragma unroll
        for (int c = 0; c < CCH; ++c) {
            const uint4 av = *(const uint4*)&s1[cur][c][lw * 4];
            const uint4 wa = *(const uint4*)&s2[cur][c][(t0 >> 1)];
            const uint4 wb = *(const uint4*)&s2[cur][c][(t0 >> 1) + 4];
            float a[8] = { bflo(av.x), bfhi(av.x), bflo(av.y), bfhi(av.y),
                           bflo(av.z), bfhi(av.z), bflo(av.w), bfhi(av.w) };
            float wn[16] = { bflo(wa.x), bfhi(wa.x), bflo(wa.y), bfhi(wa.y),
                             bflo(wa.z), bfhi(wa.z), bflo(wa.w), bfhi(wa.w),
                             bflo(wb.x), bfhi(wb.x), bflo(wb.y), bfhi(wb.y),
                             bflo(wb.z), bfhi(wb.z), bflo(wb.w), bfhi(wb.w) };
            #pragma unroll
            for (int di = 0; di < 8; ++di)
                #pragma unroll
                for (int wi = 0; wi < 8; ++wi)
                    acc[di][wi] += a[wi] * wn[di + wi];
        }
        if (k + 1 < NCH) commit((k + 1) & 1);
        __syncthreads();
    }

    // epilogue: per di, lanes 0-31 cover one d-row's 256 w (2x float4 each)
    const float sc = 1.0f / (float)CC;
    #pragma unroll
    for (int di = 0; di < 8; ++di) {
        const int d = dloc + di;
        float* po = out + (((size_t)b * DD + d) * HH + h) * WW + wbase + lw * 8;
        float4 o0 = make_float4(acc[di][0] * sc, acc[di][1] * sc,
                                acc[di][2] * sc, acc[di][3] * sc);
        float4 o1 = make_float4(acc[di][4] * sc, acc[di][5] * sc,
                                acc[di][6] * sc, acc[di][7] * sc);
        ((float4*)po)[0] = o0;
        ((float4*)po)[1] = o1;
    }
}

extern "C" void kernel_launch(void* const* d_in, const int* in_sizes, int n_in,
                              void* d_out, int out_size, void* d_ws, size_t ws_size,
                              hipStream_t stream) {
    const float* in1 = (const float*)d_in[0];
    const float* in2 = (const float*)d_in[1];
    float* out = (float*)d_out;
    const int nblocks = BB * HH * 2;          // 2048
    disp_corr_kernel<<<nblocks, NT, 0, stream>>>(in1, in2, out);
}

// Round 6
// 193.680 us; speedup vs baseline: 4.8067x; 1.1651x over previous
//
#include <hip/hip_runtime.h>

// DispCorrLayer: out[b,d,h,w] = (1/C) * sum_c in1[b,c,h,w] * in2[b,c,h,w-(D-d)]
// (zero when w + d < D). B=4 C=32 H=256 W=512 D=128, fp32.
//
// R6: banded-GEMM MFMA formulation. Per (b,h): G = in1^T (W x C) x in2 (C x W),
// out[d,w] = G[w, w+d-128]. Stage in1^T / in2^T (halo-zeroed) as bf16 [w][c]
// in LDS with XOR-swizzled 16B k-chunks; compute the 128-wide band as 32x9
// 16x16 tiles via v_mfma_f32_16x16x32_bf16 (K=32 in one instr); masked
// per-diagonal scalar stores (4 lanes/64B line per instr, L2 merges).

#define BB 4
#define CC 32
#define HH 256
#define WW 512
#define DD 128
#define NT 512
#define HW (HH * WW)

typedef __attribute__((ext_vector_type(8))) short bf16x8;
typedef __attribute__((ext_vector_type(4))) float f32x4;

__device__ __forceinline__ unsigned int pack2(float a, float b) {
    // RNE bf16 round: a -> low half, b -> high half
    union { float f; unsigned int i; } x, y; x.f = a; y.f = b;
    unsigned int xi = x.i + 0x7fffu + ((x.i >> 16) & 1u);
    unsigned int yi = y.i + 0x7fffu + ((y.i >> 16) & 1u);
    return (xi >> 16) | (yi & 0xffff0000u);
}

// uint index of the 16B chunk holding row `row`, k-chunk `kc` (8 bf16).
// XOR swizzle spreads the 4 k-chunks across banks between adjacent rows.
__device__ __forceinline__ int cidx(int row, int kc) {
    return (row * 4 + (kc ^ ((row >> 1) & 3))) * 4;
}

__global__ __launch_bounds__(NT, 2)
void disp_corr_kernel(const float* __restrict__ in1,
                      const float* __restrict__ in2,
                      float* __restrict__ out) {
    __shared__ unsigned int s1t[WW * 16];          // in1^T bf16 [512][32], 32 KB
    __shared__ unsigned int s2t[(WW + DD) * 16];   // in2^T bf16 [640][32], 40 KB

    const int t = threadIdx.x;
    const int h = blockIdx.x & (HH - 1);
    const int b = blockIdx.x >> 8;

    const float* p1 = in1 + (size_t)b * CC * HW + (size_t)h * WW;
    const float* p2 = in2 + (size_t)b * CC * HW + (size_t)h * WW;

    // ---- stage in1^T: thread t owns w = t; 8 coalesced dword loads per kc ----
    #pragma unroll
    for (int kc = 0; kc < 4; ++kc) {
        unsigned int u[4];
        #pragma unroll
        for (int ci = 0; ci < 4; ++ci) {
            const float lo = p1[(size_t)(kc * 8 + 2 * ci) * HW + t];
            const float hi = p1[(size_t)(kc * 8 + 2 * ci + 1) * HW + t];
            u[ci] = pack2(lo, hi);
        }
        *(uint4*)&s1t[cidx(t, kc)] = make_uint4(u[0], u[1], u[2], u[3]);
    }
    // ---- stage in2^T with left halo of 128 zero columns ----
    for (int idx = t; idx < WW + DD; idx += NT) {
        const int wp = idx - DD;
        #pragma unroll
        for (int kc = 0; kc < 4; ++kc) {
            unsigned int u[4] = {0u, 0u, 0u, 0u};
            if (wp >= 0) {
                #pragma unroll
                for (int ci = 0; ci < 4; ++ci) {
                    const float lo = p2[(size_t)(kc * 8 + 2 * ci) * HW + wp];
                    const float hi = p2[(size_t)(kc * 8 + 2 * ci + 1) * HW + wp];
                    u[ci] = pack2(lo, hi);
                }
            }
            *(uint4*)&s2t[cidx(idx, kc)] = make_uint4(u[0], u[1], u[2], u[3]);
        }
    }
    __syncthreads();

    // ---- banded GEMM: wave wv owns w-tiles i = 4wv..4wv+3; 9 m-tiles each ----
    const int lane = t & 63;
    const int wv   = t >> 6;
    const int cl   = lane & 15;        // fragment row/col within tile
    const int rg   = lane >> 4;        // k-chunk group 0..3
    const float sc = 1.0f / (float)CC;
    const size_t obase = ((size_t)b * DD) * HW + (size_t)h * WW;

    #pragma unroll
    for (int ii = 0; ii < 4; ++ii) {
        const int i = wv * 4 + ii;                 // w-tile index 0..31
        union { uint4 u; bf16x8 v; } a;
        a.u = *(const uint4*)&s1t[cidx(i * 16 + cl, rg)];
        #pragma unroll
        for (int mm = 0; mm <= 8; ++mm) {          // (w'+128)-tile = i + mm
            union { uint4 u; bf16x8 v; } bq;
            bq.u = *(const uint4*)&s2t[cidx((i + mm) * 16 + cl, rg)];
            f32x4 acc = {0.f, 0.f, 0.f, 0.f};
            acc = __builtin_amdgcn_mfma_f32_16x16x32_bf16(a.v, bq.v, acc, 0, 0, 0);
            // element (reg q, lane): row r = 4*rg+q (w), col cl (w'), d = 16mm+cl-r
            #pragma unroll
            for (int q = 0; q < 4; ++q) {
                const int r = rg * 4 + q;
                const int d = mm * 16 + cl - r;
                const bool ok = (mm == 0) ? (cl >= r)
                              : (mm == 8) ? (cl < r) : true;
                if (ok)
                    out[obase + (size_t)d * HW + i * 16 + r] = acc[q] * sc;
            }
        }
    }
}

extern "C" void kernel_launch(void* const* d_in, const int* in_sizes, int n_in,
                              void* d_out, int out_size, void* d_ws, size_t ws_size,
                              hipStream_t stream) {
    const float* in1 = (const float*)d_in[0];
    const float* in2 = (const float*)d_in[1];
    float* out = (float*)d_out;
    const int nblocks = BB * HH;               // 1024: one block per (b,h)
    disp_corr_kernel<<<nblocks, NT, 0, stream>>>(in1, in2, out);
}

// Round 7
// 114.609 us; speedup vs baseline: 8.1230x; 1.6899x over previous
//
#include <hip/hip_runtime.h>

// DispCorrLayer: out[b,d,h,w] = (1/C) * sum_c in1[b,c,h,w] * in2[b,c,h,w-(D-d)]
// (zero when w + d < D). B=4 C=32 H=256 W=512 D=128, fp32.
//
// R7: R6's banded-GEMM MFMA core + LDS diagonal-transpose epilogue.
// Per block (b, h, w-half of 256): stage in1^T [256][32] and in2^T halo
// [384][32] as bf16 (k-chunk XOR swizzle). Each wave computes 4 w-tiles x
// 9 m-tiles of G = in1^T x in2 via mfma_f32_16x16x32_bf16, scatters the
// diagonal band into a wave-private ob[128][17] (odd stride -> 4-way max
// bank aliasing), then stores d-row-major as fully-coalesced float4
// (16 complete 64B lines per store instr vs R6's 64 partial lines).

#define BB 4
#define CC 32
#define HH 256
#define WW 512
#define DD 128
#define HW (HH * WW)

#define NT 256               // 4 waves
#define WHALF 256            // w span per block
#define S2N 384              // staged in2 cols: w' in [wb-128, wb+256)
#define OBS 17               // ob row stride (words); odd => bank spread

typedef __attribute__((ext_vector_type(8))) short bf16x8;
typedef __attribute__((ext_vector_type(4))) float f32x4;

__device__ __forceinline__ unsigned int pack2(float a, float b) {
    // RNE bf16 round: a -> low half, b -> high half
    union { float f; unsigned int i; } x, y; x.f = a; y.f = b;
    unsigned int xi = x.i + 0x7fffu + ((x.i >> 16) & 1u);
    unsigned int yi = y.i + 0x7fffu + ((y.i >> 16) & 1u);
    return (xi >> 16) | (yi & 0xffff0000u);
}

// word index of the 16B chunk holding row `row`, k-chunk `kc` (8 bf16).
__device__ __forceinline__ int cidx(int row, int kc) {
    return (row * 4 + (kc ^ ((row >> 1) & 3))) * 4;
}

__global__ __launch_bounds__(NT, 2)
void disp_corr_kernel(const float* __restrict__ in1,
                      const float* __restrict__ in2,
                      float* __restrict__ out) {
    __shared__ unsigned int s1t[WHALF * 16];     // in1^T bf16, 16 KB
    __shared__ unsigned int s2t[S2N * 16];       // in2^T bf16 + halo, 24 KB
    __shared__ float ob[4][DD * OBS];            // per-wave band buf, 34 KB

    const int t = threadIdx.x;

    // XCD swizzle (bijective, 2048 = 8*256): consecutive work units (w-half
    // pairs, adjacent h) share an XCD for in2-halo L2 reuse.
    const int xcd = blockIdx.x & 7, slot = blockIdx.x >> 3;
    const int work = (xcd << 8) + slot;
    const int wh = work & 1;
    const int h  = (work >> 1) & (HH - 1);
    const int b  = work >> 9;
    const int wb = wh * WHALF;

    const float* p1 = in1 + (size_t)b * CC * HW + (size_t)h * WW + wb;
    const float* p2 = in2 + (size_t)b * CC * HW + (size_t)h * WW;

    // ---- stage in1^T: thread t owns local col w = t ----
    #pragma unroll
    for (int kc = 0; kc < 4; ++kc) {
        unsigned int u[4];
        #pragma unroll
        for (int ci = 0; ci < 4; ++ci) {
            const float lo = p1[(size_t)(kc * 8 + 2 * ci) * HW + t];
            const float hi = p1[(size_t)(kc * 8 + 2 * ci + 1) * HW + t];
            u[ci] = pack2(lo, hi);
        }
        *(uint4*)&s1t[cidx(t, kc)] = make_uint4(u[0], u[1], u[2], u[3]);
    }
    // ---- stage in2^T with halo: local col idx <-> w' = wb + idx - 128 ----
    #pragma unroll
    for (int rep = 0; rep < 2; ++rep) {
        const int idx = t + rep * NT;
        if (idx < S2N) {
            const int wp = wb + idx - DD;        // always < WW
            #pragma unroll
            for (int kc = 0; kc < 4; ++kc) {
                unsigned int u[4] = {0u, 0u, 0u, 0u};
                if (wp >= 0) {
                    #pragma unroll
                    for (int ci = 0; ci < 4; ++ci) {
                        const float lo = p2[(size_t)(kc * 8 + 2 * ci) * HW + wp];
                        const float hi = p2[(size_t)(kc * 8 + 2 * ci + 1) * HW + wp];
                        u[ci] = pack2(lo, hi);
                    }
                }
                *(uint4*)&s2t[cidx(idx, kc)] = make_uint4(u[0], u[1], u[2], u[3]);
            }
        }
    }
    __syncthreads();

    // ---- per wave: 4 w-tiles; per tile: 9 MFMA -> ob scatter -> store ----
    const int lane = t & 63;
    const int wv   = t >> 6;
    const int cl   = lane & 15;       // fragment col (w' within tile)
    const int rg   = lane >> 4;       // fragment row group (w)
    float* myob = ob[wv];
    const float sc = 1.0f / (float)CC;
    const size_t obase = (size_t)b * DD * HW + (size_t)h * WW + wb;

    const int dq = lane >> 2;         // store phase: d within 16-group
    const int j  = lane & 3;          // store phase: w-quad

    for (int ii = 0; ii < 4; ++ii) {
        const int i = wv * 4 + ii;                 // local w-tile 0..15
        union { uint4 u; bf16x8 v; } a;
        a.u = *(const uint4*)&s1t[cidx(i * 16 + cl, rg)];
        #pragma unroll
        for (int mm = 0; mm <= 8; ++mm) {
            union { uint4 u; bf16x8 v; } bq;
            bq.u = *(const uint4*)&s2t[cidx((i + mm) * 16 + cl, rg)];
            f32x4 acc = {0.f, 0.f, 0.f, 0.f};
            acc = __builtin_amdgcn_mfma_f32_16x16x32_bf16(a.v, bq.v, acc, 0, 0, 0);
            // element (reg q): row r = 4rg+q (w), col cl (w'), d = 16mm+cl-r
            #pragma unroll
            for (int q = 0; q < 4; ++q) {
                const int r = rg * 4 + q;
                const int d = mm * 16 + cl - r;
                const bool ok = (mm == 0) ? (cl >= r)
                              : (mm == 8) ? (cl < r) : true;
                if (ok) myob[d * OBS + r] = acc[q];
            }
        }
        // coalesced store: instr = 16 d-planes x one full 64B line each
        #pragma unroll
        for (int dg = 0; dg < 8; ++dg) {
            const int d = dg * 16 + dq;
            const float* rp = &myob[d * OBS + 4 * j];
            float4 v = make_float4(rp[0] * sc, rp[1] * sc,
                                   rp[2] * sc, rp[3] * sc);
            *(float4*)(out + obase + (size_t)d * HW + i * 16 + 4 * j) = v;
        }
    }
}

extern "C" void kernel_launch(void* const* d_in, const int* in_sizes, int n_in,
                              void* d_out, int out_size, void* d_ws, size_t ws_size,
                              hipStream_t stream) {
    const float* in1 = (const float*)d_in[0];
    const float* in2 = (const float*)d_in[1];
    float* out = (float*)d_out;
    const int nblocks = BB * HH * 2;             // 2048
    disp_corr_kernel<<<nblocks, NT, 0, stream>>>(in1, in2, out);
}

// Round 8
// 91.237 us; speedup vs baseline: 10.2039x; 1.2562x over previous
//
#include <hip/hip_runtime.h>

// DispCorrLayer: out[b,d,h,w] = (1/C) * sum_c in1[b,c,h,w] * in2[b,c,h,w-(D-d)]
// (zero when w + d < D). B=4 C=32 H=256 W=512 D=128, fp32.
//
// R8 = R7 (banded-GEMM MFMA + LDS diagonal-transpose epilogue) with:
//  - OBS 17->20: ob rows 16B-aligned -> readback is 1 ds_read_b128 per 16
//    outputs (was 4 scalar ds_read_b32). LDS = 80KB exactly -> 2 blocks/CU.
//  - 1/32 scale folded into in1 bf16 staging (2^-5, exact) -> epilogue is a
//    pure LDS->reg->global move.
//  - staging global loads hoisted into register arrays (96-deep MLP) before
//    any pack/ds_write.
//  - non-temporal output stores (write-once stream, skip L2).

#define BB 4
#define CC 32
#define HH 256
#define WW 512
#define DD 128
#define HW (HH * WW)

#define NT 256               // 4 waves
#define WHALF 256            // w span per block
#define S2N 384              // staged in2 cols: w' in [wb-128, wb+256)
#define OBS 20               // ob row stride (words): 16B-aligned rows + spread

typedef __attribute__((ext_vector_type(8))) short bf16x8;
typedef __attribute__((ext_vector_type(4))) float f32x4;

__device__ __forceinline__ unsigned int pack2(float a, float b) {
    // RNE bf16 round: a -> low half, b -> high half
    union { float f; unsigned int i; } x, y; x.f = a; y.f = b;
    unsigned int xi = x.i + 0x7fffu + ((x.i >> 16) & 1u);
    unsigned int yi = y.i + 0x7fffu + ((y.i >> 16) & 1u);
    return (xi >> 16) | (yi & 0xffff0000u);
}

// word index of the 16B chunk holding row `row`, k-chunk `kc` (8 bf16).
__device__ __forceinline__ int cidx(int row, int kc) {
    return (row * 4 + (kc ^ ((row >> 1) & 3))) * 4;
}

__global__ __launch_bounds__(NT, 2)
void disp_corr_kernel(const float* __restrict__ in1,
                      const float* __restrict__ in2,
                      float* __restrict__ out) {
    __shared__ __align__(16) unsigned int s1t[WHALF * 16];  // in1^T bf16, 16 KB
    __shared__ __align__(16) unsigned int s2t[S2N * 16];    // in2^T bf16, 24 KB
    __shared__ __align__(16) float ob[4][DD * OBS];         // band buf, 40 KB

    const int t = threadIdx.x;

    // XCD swizzle (bijective, 2048 = 8*256)
    const int xcd = blockIdx.x & 7, slot = blockIdx.x >> 3;
    const int work = (xcd << 8) + slot;
    const int wh = work & 1;
    const int h  = (work >> 1) & (HH - 1);
    const int b  = work >> 9;
    const int wb = wh * WHALF;

    const float* p1 = in1 + (size_t)b * CC * HW + (size_t)h * WW + wb;
    const float* p2 = in2 + (size_t)b * CC * HW + (size_t)h * WW;

    // ---- issue ALL staging loads first (96-deep MLP) ----
    const float sc = 1.0f / (float)CC;
    float v1[CC], v2[CC], v3[CC];
    #pragma unroll
    for (int c = 0; c < CC; ++c) v1[c] = p1[(size_t)c * HW + t];
    const int wp0 = wb + t - DD;
    if (wp0 >= 0) {
        #pragma unroll
        for (int c = 0; c < CC; ++c) v2[c] = p2[(size_t)c * HW + wp0];
    } else {
        #pragma unroll
        for (int c = 0; c < CC; ++c) v2[c] = 0.f;
    }
    const bool rep1 = (t < S2N - NT);                // t < 128
    const int wp1 = wb + DD + t;                     // always in [128, 512)
    if (rep1) {
        #pragma unroll
        for (int c = 0; c < CC; ++c) v3[c] = p2[(size_t)c * HW + wp1];
    }

    // ---- pack + commit to LDS ----
    #pragma unroll
    for (int kc = 0; kc < 4; ++kc) {
        unsigned int u[4];
        #pragma unroll
        for (int ci = 0; ci < 4; ++ci)
            u[ci] = pack2(v1[kc * 8 + 2 * ci] * sc, v1[kc * 8 + 2 * ci + 1] * sc);
        *(uint4*)&s1t[cidx(t, kc)] = make_uint4(u[0], u[1], u[2], u[3]);
    }
    #pragma unroll
    for (int kc = 0; kc < 4; ++kc) {
        unsigned int u[4];
        #pragma unroll
        for (int ci = 0; ci < 4; ++ci)
            u[ci] = pack2(v2[kc * 8 + 2 * ci], v2[kc * 8 + 2 * ci + 1]);
        *(uint4*)&s2t[cidx(t, kc)] = make_uint4(u[0], u[1], u[2], u[3]);
    }
    if (rep1) {
        #pragma unroll
        for (int kc = 0; kc < 4; ++kc) {
            unsigned int u[4];
            #pragma unroll
            for (int ci = 0; ci < 4; ++ci)
                u[ci] = pack2(v3[kc * 8 + 2 * ci], v3[kc * 8 + 2 * ci + 1]);
            *(uint4*)&s2t[cidx(NT + t, kc)] = make_uint4(u[0], u[1], u[2], u[3]);
        }
    }
    __syncthreads();

    // ---- per wave: 4 w-tiles; per tile: 9 MFMA -> ob scatter -> b128 store ----
    const int lane = t & 63;
    const int wv   = t >> 6;
    const int cl   = lane & 15;       // fragment col (w' within tile)
    const int rg   = lane >> 4;       // fragment row group (w)
    float* myob = ob[wv];
    const size_t obase = (size_t)b * DD * HW + (size_t)h * WW + wb;

    const int dq = lane >> 2;         // store phase: d within 16-group
    const int j  = lane & 3;          // store phase: w-quad

    #pragma unroll
    for (int ii = 0; ii < 4; ++ii) {
        const int i = wv * 4 + ii;                 // local w-tile 0..15
        union { uint4 u; bf16x8 v; } a;
        a.u = *(const uint4*)&s1t[cidx(i * 16 + cl, rg)];
        #pragma unroll
        for (int mm = 0; mm <= 8; ++mm) {
            union { uint4 u; bf16x8 v; } bq;
            bq.u = *(const uint4*)&s2t[cidx((i + mm) * 16 + cl, rg)];
            f32x4 acc = {0.f, 0.f, 0.f, 0.f};
            acc = __builtin_amdgcn_mfma_f32_16x16x32_bf16(a.v, bq.v, acc, 0, 0, 0);
            // element (reg q): row r = 4rg+q (w), col cl (w'), d = 16mm+cl-r
            #pragma unroll
            for (int q = 0; q < 4; ++q) {
                const int r = rg * 4 + q;
                const int d = mm * 16 + cl - r;
                const bool ok = (mm == 0) ? (cl >= r)
                              : (mm == 8) ? (cl < r) : true;
                if (ok) myob[d * OBS + r] = acc[q];
            }
        }
        // coalesced store: instr = 16 d-planes x one full 64B line each
        #pragma unroll
        for (int dg = 0; dg < 8; ++dg) {
            const int d = dg * 16 + dq;
            f32x4 v = *(const f32x4*)&myob[d * OBS + 4 * j];
            __builtin_nontemporal_store(
                v, (f32x4*)(out + obase + (size_t)d * HW + i * 16 + 4 * j));
        }
    }
}

extern "C" void kernel_launch(void* const* d_in, const int* in_sizes, int n_in,
                              void* d_out, int out_size, void* d_ws, size_t ws_size,
                              hipStream_t stream) {
    const float* in1 = (const float*)d_in[0];
    const float* in2 = (const float*)d_in[1];
    float* out = (float*)d_out;
    const int nblocks = BB * HH * 2;             // 2048
    disp_corr_kernel<<<nblocks, NT, 0, stream>>>(in1, in2, out);
}